// Round 10
// baseline (1444.410 us; speedup 1.0000x reference)
//
#include <hip/hip_runtime.h>
#include <hip/hip_bf16.h>
#include <hip/hip_fp16.h>
#include <math.h>

#define NN 20000
#define EE 320000
#define GG 64
#define IND 256
#define HD 256
#define CC 2

typedef __hip_bfloat16 bf16;

__device__ __forceinline__ float b2f(bf16 x){ return __bfloat162float(x); }
__device__ __forceinline__ float bits2f(unsigned short b){
    union{ float f; unsigned u; } v; v.u = ((unsigned)b) << 16; return v.f;
}
// float load by code: 0=fp32, 1=bf16, 2=fp16
__device__ __forceinline__ float ldf3(const void* p, size_t i, int c){
    if (c == 1) return b2f(((const bf16*)p)[i]);
    if (c == 2) return __half2float(((const __half*)p)[i]);
    return ((const float*)p)[i];
}

// ---- float dtype detection on 64 even 16-bit halves (128B window) ----
__global__ void k_dtype(const unsigned short* h, const unsigned short* Wc,
                        const unsigned short* wg, const unsigned short* W1,
                        const unsigned short* W2, const unsigned short* bc,
                        int* dcode){
    int t = threadIdx.x; if (t >= 6) return;
    const unsigned short* p = t==0?h:t==1?Wc:t==2?wg:t==3?W1:t==4?W2:bc;
    int cb = 0, cf = 0, nz = 0;
    for (int i = 0; i < 128; i += 2){
        unsigned u = p[i];
        nz += (u != 0);
        int e8 = (u >> 7) & 0xFF;
        int e5 = (u >> 10) & 0x1F;
        cb += (e8 >= 100 && e8 <= 141);
        cf += (e5 >= 4 && e5 <= 22);
    }
    dcode[t] = (nz < 8) ? 0 : (cb >= 60) ? 1 : ((cf >= 60) ? 2 : 0);
}

// ---- int format detection: 0=int32, 1=int64, 2=fp32-encoded, 3=fp16-encoded ----
__global__ void k_idet4(const void* buf, int n, int bound, int* code){
    if (threadIdx.x != 0) return;
    int ok64 = 1, ok32 = 1, okf32 = 1, okf16 = 1;
    const long long* p64 = (const long long*)buf;
    for (int i = 0; i < 64; i++){
        long long v = p64[n/8 + i];
        if (v < 0 || v >= (long long)bound) ok64 = 0;
    }
    const int* p32 = (const int*)buf;
    const unsigned* pu = (const unsigned*)buf;
    for (int i = 0; i < 64; i++){
        int v = p32[n/4 + i];
        if (v < 0 || v >= bound) ok32 = 0;
        float f = __uint_as_float(pu[n/4 + i]);
        if (!(f >= 0.f && f < (float)bound)) okf32 = 0;
    }
    const __half* ph = (const __half*)buf;
    for (int i = 0; i < 64; i++){
        float f = __half2float(ph[n/2 + i]);
        if (!(f >= 0.f && f < (float)bound)) okf16 = 0;
    }
    *code = ok64 ? 1 : (ok32 ? 0 : (okf32 ? 2 : (okf16 ? 3 : 0)));
}
__global__ void k_idecode4(const void* __restrict__ buf, int n,
                           const int* __restrict__ code, int* __restrict__ out){
    int i = blockIdx.x*256 + threadIdx.x;
    if (i >= n) return;
    int c = *code;
    int v;
    if (c == 1)      v = (int)(((const long long*)buf)[i]);
    else if (c == 2) v = (int)(((const float*)buf)[i]);
    else if (c == 3) v = (int)__half2float(((const __half*)buf)[i]);
    else             v = ((const int*)buf)[i];
    out[i] = v;
}

__global__ void k_init(float* gmax, int* gstart, int* gend){
    int g = threadIdx.x;
    if (g < GG){ gmax[g] = -INFINITY; gstart[g] = NN; gend[g] = 0; }
}

__global__ void k_deg(const int* __restrict__ src, const int* __restrict__ dst,
                      float* deg_out, float* deg_in){
    int e = blockIdx.x*256 + threadIdx.x;
    if (e >= EE) return;
    int s = src[e], d = dst[e];
    if ((unsigned)s < NN) atomicAdd(&deg_out[s], 1.f);
    if ((unsigned)d < NN) atomicAdd(&deg_in[d], 1.f);
}

__global__ void k_rs(float* deg){
    int i = blockIdx.x*256 + threadIdx.x;
    if (i >= 2*NN) return;
    deg[i] = rsqrtf(fmaxf(deg[i], 1.f));
}

// hn[N,H] = h[N,IN] @ W_conv[IN,H]  (fp32 acc, bf16 staging out)
__global__ __launch_bounds__(256) void k_gemm1(const void* __restrict__ h,
                                               const void* __restrict__ W,
                                               const int* __restrict__ dcode,
                                               bf16* __restrict__ hn){
    int fh = dcode[0], fW = dcode[1];
    __shared__ float As[32][65];
    __shared__ float Bs[32][64];
    int tid = threadIdx.x;
    int row0 = blockIdx.y*64, col0 = blockIdx.x*64;
    int tx = tid & 15, ty = tid >> 4;
    float acc[4][4] = {};
    for (int k0 = 0; k0 < IND; k0 += 32){
        #pragma unroll
        for (int j = 0; j < 8; j++){
            int idx = tid + j*256;
            int m = idx >> 5, k = idx & 31;
            int r = row0 + m;
            As[k][m] = (r < NN) ? ldf3(h, (size_t)r*IND + k0 + k, fh) : 0.f;
            int kk = idx >> 6, n = idx & 63;
            Bs[kk][n] = ldf3(W, (size_t)(k0+kk)*HD + col0 + n, fW);
        }
        __syncthreads();
        #pragma unroll
        for (int k = 0; k < 32; k++){
            float a[4], b[4];
            #pragma unroll
            for (int i = 0; i < 4; i++) a[i] = As[k][ty*4+i];
            #pragma unroll
            for (int j = 0; j < 4; j++) b[j] = Bs[k][tx*4+j];
            #pragma unroll
            for (int i = 0; i < 4; i++)
                #pragma unroll
                for (int j = 0; j < 4; j++) acc[i][j] += a[i]*b[j];
        }
        __syncthreads();
    }
    #pragma unroll
    for (int i = 0; i < 4; i++){
        int r = row0 + ty*4 + i;
        if (r < NN){
            #pragma unroll
            for (int j = 0; j < 4; j++)
                hn[(size_t)r*HD + col0 + tx*4 + j] = __float2bfloat16(acc[i][j]);
        }
    }
}

__global__ __launch_bounds__(256) void k_scatter(const bf16* __restrict__ hn,
                                                 const float* __restrict__ rs_out,
                                                 const int* __restrict__ src,
                                                 const int* __restrict__ dst,
                                                 float* __restrict__ agg){
    int e = blockIdx.x*4 + (threadIdx.x >> 6);
    if (e >= EE) return;
    int lane = threadIdx.x & 63;
    int s = src[e], d = dst[e];
    if ((unsigned)s >= NN || (unsigned)d >= NN) return;
    float rs = rs_out[s];
    ushort4 u = ((const ushort4*)(hn + (size_t)s*HD))[lane];
    float* a = agg + (size_t)d*HD + lane*4;
    atomicAdd(a+0, bits2f(u.x)*rs);
    atomicAdd(a+1, bits2f(u.y)*rs);
    atomicAdd(a+2, bits2f(u.z)*rs);
    atomicAdd(a+3, bits2f(u.w)*rs);
}

// hr = relu(agg*rs_in + b_conv) in place; gate = hr . w_gate + b_gate
__global__ __launch_bounds__(64) void k_final(float* __restrict__ agg,
                                              const float* __restrict__ rs_in,
                                              const void* __restrict__ b_conv,
                                              const void* __restrict__ w_gate,
                                              const void* __restrict__ b_gate,
                                              const int* __restrict__ dcode,
                                              float* __restrict__ gate){
    int fg = dcode[2], db = dcode[5];
    int n = blockIdx.x, lane = threadIdx.x;
    float rs = rs_in[n];
    float4 v = ((float4*)(agg + (size_t)n*HD))[lane];
    int c = lane*4;
    v.x = fmaxf(fmaf(v.x, rs, ldf3(b_conv, c+0, db)), 0.f);
    v.y = fmaxf(fmaf(v.y, rs, ldf3(b_conv, c+1, db)), 0.f);
    v.z = fmaxf(fmaf(v.z, rs, ldf3(b_conv, c+2, db)), 0.f);
    v.w = fmaxf(fmaf(v.w, rs, ldf3(b_conv, c+3, db)), 0.f);
    ((float4*)(agg + (size_t)n*HD))[lane] = v;
    float g = v.x*ldf3(w_gate, c+0, fg) + v.y*ldf3(w_gate, c+1, fg)
            + v.z*ldf3(w_gate, c+2, fg) + v.w*ldf3(w_gate, c+3, fg);
    #pragma unroll
    for (int off = 32; off; off >>= 1) g += __shfl_down(g, off);
    if (lane == 0) gate[n] = g + ldf3(b_gate, 0, db);
}

__global__ __launch_bounds__(256) void k_gmax(const int* __restrict__ gid,
                                              const float* __restrict__ gate,
                                              float* gmax, int* gstart, int* gend){
    int g = blockIdx.x, tid = threadIdx.x;
    float m = -INFINITY; int lo = NN, hi = -1;
    for (int n = tid; n < NN; n += 256){
        if (gid[n] == g){ float v = gate[n]; m = fmaxf(m, v); lo = min(lo, n); hi = max(hi, n); }
    }
    __shared__ float sm[256]; __shared__ int sl[256], sh[256];
    sm[tid] = m; sl[tid] = lo; sh[tid] = hi; __syncthreads();
    for (int s = 128; s; s >>= 1){
        if (tid < s){
            sm[tid] = fmaxf(sm[tid], sm[tid+s]);
            sl[tid] = min(sl[tid], sl[tid+s]);
            sh[tid] = max(sh[tid], sh[tid+s]);
        }
        __syncthreads();
    }
    if (tid == 0){ gmax[g] = sm[0]; gstart[g] = sl[0]; gend[g] = sh[0] + 1; }
}

__global__ void k_exps(const int* __restrict__ gid, float* __restrict__ gate,
                       const float* __restrict__ gmax, float* denom){
    int n = blockIdx.x*256 + threadIdx.x;
    if (n >= NN) return;
    int g = min(max(gid[n], 0), GG-1);
    float e = expf(fminf(gate[n] - gmax[g], 0.f));
    gate[n] = e;
    atomicAdd(&denom[g], e);
}

__global__ void k_att(const int* __restrict__ gid, float* __restrict__ gate,
                      const float* __restrict__ denom, float* __restrict__ out_att){
    int n = blockIdx.x*256 + threadIdx.x;
    if (n >= NN) return;
    int g = min(max(gid[n], 0), GG-1);
    float a = gate[n] / denom[g];
    gate[n] = a;
    out_att[n] = a;
}

__global__ __launch_bounds__(256) void k_hg(const float* __restrict__ att,
                                            const float* __restrict__ hr,
                                            const int* __restrict__ gstart,
                                            const int* __restrict__ gend,
                                            float* __restrict__ hg){
    int g = blockIdx.x >> 3, part = blockIdx.x & 7;
    int c = threadIdx.x;
    int s = gstart[g], en = gend[g];
    int len = en - s;
    if (len <= 0) return;
    int chunk = (len + 7) >> 3;
    int lo = s + part*chunk, hi = min(lo + chunk, en);
    if (lo >= hi) return;
    float acc = 0.f;
    for (int n = lo; n < hi; n++) acc += att[n] * hr[(size_t)n*HD + c];
    atomicAdd(&hg[g*HD + c], acc);
}

__global__ __launch_bounds__(256) void k_cls(const float* __restrict__ hg,
                                             const void* __restrict__ W1,
                                             const void* __restrict__ b1,
                                             const void* __restrict__ W2,
                                             const void* __restrict__ b2,
                                             const int* __restrict__ dcode,
                                             float* __restrict__ out0,
                                             float* __restrict__ out_hg){
    int f1 = dcode[3], f2 = dcode[4], db = dcode[5];
    int g = blockIdx.x, tid = threadIdx.x;
    __shared__ float hs[256];
    float hv = hg[g*HD + tid];
    hs[tid] = hv;
    out_hg[g*HD + tid] = hv;
    __syncthreads();
    float acc = ldf3(b1, tid, db);
    if (f1 == 1){
        const bf16* w = (const bf16*)W1;
        for (int k = 0; k < HD; k++) acc += hs[k]*b2f(w[(size_t)k*HD + tid]);
    } else if (f1 == 2){
        const __half* w = (const __half*)W1;
        for (int k = 0; k < HD; k++) acc += hs[k]*__half2float(w[(size_t)k*HD + tid]);
    } else {
        const float* w = (const float*)W1;
        for (int k = 0; k < HD; k++) acc += hs[k]*w[(size_t)k*HD + tid];
    }
    float p0 = acc * ldf3(W2, tid*CC + 0, f2);
    float p1 = acc * ldf3(W2, tid*CC + 1, f2);
    __shared__ float r0[256], r1[256];
    r0[tid] = p0; r1[tid] = p1; __syncthreads();
    for (int s = 128; s; s >>= 1){
        if (tid < s){ r0[tid] += r0[tid+s]; r1[tid] += r1[tid+s]; }
        __syncthreads();
    }
    if (tid == 0){
        float a0 = r0[0] + ldf3(b2, 0, db);
        float a1 = r1[0] + ldf3(b2, 1, db);
        out0[g*CC+0] = 1.f/(1.f + expf(-a0));
        out0[g*CC+1] = 1.f/(1.f + expf(-a1));
    }
}

extern "C" void kernel_launch(void* const* d_in, const int* in_sizes, int n_in,
                              void* d_out, int out_size, void* d_ws, size_t ws_size,
                              hipStream_t stream) {
    const void* h      = d_in[0];
    const void* src_r  = d_in[1];
    const void* dst_r  = d_in[2];
    const void* gid_r  = d_in[3];
    const void* W_conv = d_in[4];
    const void* b_conv = d_in[5];
    const void* w_gate = d_in[6];
    const void* b_gate = d_in[7];
    const void* W1     = d_in[8];
    const void* b1     = d_in[9];
    const void* W2     = d_in[10];
    const void* b2     = d_in[11];

    // OUTPUT IS FP32 (reference returns float32; R9 beacon experiment proved it)
    float* out     = (float*)d_out;
    float* out0    = out;                    // [G,C]   = 128
    float* out_att = out + GG*CC;            // [N]     = 20000
    float* out_hg  = out + GG*CC + NN;       // [G,H]   = 16384

    char* w = (char*)d_ws;
    float* agg  = (float*)w;  w += (size_t)NN*HD*sizeof(float);
    bf16*  hn   = (bf16*)w;   w += (size_t)NN*HD*sizeof(bf16);
    float* deg  = (float*)w;  w += (size_t)2*NN*sizeof(float);
    float* deg_out = deg;
    float* deg_in  = deg + NN;
    float* gate = (float*)w;  w += (size_t)NN*sizeof(float);
    float* gmax = (float*)w;  w += GG*sizeof(float);
    float* denom= (float*)w;  w += GG*sizeof(float);
    float* hg   = (float*)w;  w += (size_t)GG*HD*sizeof(float);
    int* gstart = (int*)w;    w += GG*sizeof(int);
    int* gend   = (int*)w;    w += GG*sizeof(int);
    int* dcode  = (int*)w;    w += 8*sizeof(int);
    int* icode  = (int*)w;    w += 8*sizeof(int);
    int* src_i  = (int*)w;    w += (size_t)EE*sizeof(int);
    int* dst_i  = (int*)w;    w += (size_t)EE*sizeof(int);
    int* gid_i  = (int*)w;    w += (size_t)NN*sizeof(int);

    k_dtype<<<1, 64, 0, stream>>>((const unsigned short*)h, (const unsigned short*)W_conv,
                                  (const unsigned short*)w_gate, (const unsigned short*)W1,
                                  (const unsigned short*)W2, (const unsigned short*)b_conv,
                                  dcode);
    k_idet4<<<1, 64, 0, stream>>>(src_r, EE, NN, icode+0);
    k_idet4<<<1, 64, 0, stream>>>(dst_r, EE, NN, icode+1);
    k_idet4<<<1, 64, 0, stream>>>(gid_r, NN, GG, icode+2);
    k_idecode4<<<(EE+255)/256, 256, 0, stream>>>(src_r, EE, icode+0, src_i);
    k_idecode4<<<(EE+255)/256, 256, 0, stream>>>(dst_r, EE, icode+1, dst_i);
    k_idecode4<<<(NN+255)/256, 256, 0, stream>>>(gid_r, NN, icode+2, gid_i);

    hipMemsetAsync(agg, 0, (size_t)NN*HD*sizeof(float), stream);
    hipMemsetAsync(deg, 0, (size_t)2*NN*sizeof(float), stream);
    hipMemsetAsync(denom, 0, (size_t)(GG + GG*HD)*sizeof(float), stream);
    k_init<<<1, 64, 0, stream>>>(gmax, gstart, gend);

    k_deg<<<(EE+255)/256, 256, 0, stream>>>(src_i, dst_i, deg_out, deg_in);
    k_rs<<<(2*NN+255)/256, 256, 0, stream>>>(deg);

    dim3 g1(HD/64, (NN+63)/64);
    k_gemm1<<<g1, 256, 0, stream>>>(h, W_conv, dcode, hn);

    k_scatter<<<(EE+3)/4, 256, 0, stream>>>(hn, deg_out, src_i, dst_i, agg);
    k_final<<<NN, 64, 0, stream>>>(agg, deg_in, b_conv, w_gate, b_gate, dcode, gate);

    k_gmax<<<GG, 256, 0, stream>>>(gid_i, gate, gmax, gstart, gend);
    k_exps<<<(NN+255)/256, 256, 0, stream>>>(gid_i, gate, gmax, denom);
    k_att<<<(NN+255)/256, 256, 0, stream>>>(gid_i, gate, denom, out_att);
    k_hg<<<GG*8, 256, 0, stream>>>(gate, agg, gstart, gend, hg);
    k_cls<<<GG, 256, 0, stream>>>(hg, W1, b1, W2, b2, dcode, out0, out_hg);
}

// Round 11
// 482.951 us; speedup vs baseline: 2.9908x; 2.9908x over previous
//
#include <hip/hip_runtime.h>
#include <hip/hip_bf16.h>
#include <hip/hip_fp16.h>
#include <math.h>

#define NN 20000
#define EE 320000
#define GG 64
#define IND 256
#define HD 256
#define CC 2

typedef __hip_bfloat16 bf16;

__device__ __forceinline__ float b2f(bf16 x){ return __bfloat162float(x); }
__device__ __forceinline__ float bits2f(unsigned short b){
    union{ float f; unsigned u; } v; v.u = ((unsigned)b) << 16; return v.f;
}
// float load by code: 0=fp32, 1=bf16, 2=fp16
__device__ __forceinline__ float ldf3(const void* p, size_t i, int c){
    if (c == 1) return b2f(((const bf16*)p)[i]);
    if (c == 2) return __half2float(((const __half*)p)[i]);
    return ((const float*)p)[i];
}

// ---- float dtype detection (insurance; expected all fp32) ----
__global__ void k_dtype(const unsigned short* h, const unsigned short* Wc,
                        const unsigned short* wg, const unsigned short* W1,
                        const unsigned short* W2, const unsigned short* bc,
                        int* dcode){
    int t = threadIdx.x; if (t >= 6) return;
    const unsigned short* p = t==0?h:t==1?Wc:t==2?wg:t==3?W1:t==4?W2:bc;
    int cb = 0, cf = 0, nz = 0;
    for (int i = 0; i < 128; i += 2){
        unsigned u = p[i];
        nz += (u != 0);
        int e8 = (u >> 7) & 0xFF;
        int e5 = (u >> 10) & 0x1F;
        cb += (e8 >= 100 && e8 <= 141);
        cf += (e5 >= 4 && e5 <= 22);
    }
    dcode[t] = (nz < 8) ? 0 : (cb >= 60) ? 1 : ((cf >= 60) ? 2 : 0);
}

// ---- int format detection: 0=int32, 1=int64, 2=fp32-enc, 3=fp16-enc ----
__global__ void k_idet4(const void* buf, int n, int bound, int* code){
    if (threadIdx.x != 0) return;
    int ok64 = 1, ok32 = 1, okf32 = 1, okf16 = 1;
    const long long* p64 = (const long long*)buf;
    for (int i = 0; i < 64; i++){
        long long v = p64[n/8 + i];
        if (v < 0 || v >= (long long)bound) ok64 = 0;
    }
    const int* p32 = (const int*)buf;
    const unsigned* pu = (const unsigned*)buf;
    for (int i = 0; i < 64; i++){
        int v = p32[n/4 + i];
        if (v < 0 || v >= bound) ok32 = 0;
        float f = __uint_as_float(pu[n/4 + i]);
        if (!(f >= 0.f && f < (float)bound)) okf32 = 0;
    }
    const __half* ph = (const __half*)buf;
    for (int i = 0; i < 64; i++){
        float f = __half2float(ph[n/2 + i]);
        if (!(f >= 0.f && f < (float)bound)) okf16 = 0;
    }
    *code = ok64 ? 1 : (ok32 ? 0 : (okf32 ? 2 : (okf16 ? 3 : 0)));
}
__global__ void k_idecode4(const void* __restrict__ buf, int n,
                           const int* __restrict__ code, int* __restrict__ out){
    int i = blockIdx.x*256 + threadIdx.x;
    if (i >= n) return;
    int c = *code;
    int v;
    if (c == 1)      v = (int)(((const long long*)buf)[i]);
    else if (c == 2) v = (int)(((const float*)buf)[i]);
    else if (c == 3) v = (int)__half2float(((const __half*)buf)[i]);
    else             v = ((const int*)buf)[i];
    out[i] = v;
}

__global__ void k_init(float* gmax, int* gstart, int* gend){
    int g = threadIdx.x;
    if (g < GG){ gmax[g] = -INFINITY; gstart[g] = NN; gend[g] = 0; }
}

// degrees: float (for rsqrt) + int in-degree counts (for CSR)
__global__ void k_deg(const int* __restrict__ src, const int* __restrict__ dst,
                      float* deg_out, float* deg_in, int* cnt_in){
    int e = blockIdx.x*256 + threadIdx.x;
    if (e >= EE) return;
    int s = src[e], d = dst[e];
    if ((unsigned)s < NN) atomicAdd(&deg_out[s], 1.f);
    if ((unsigned)d < NN){ atomicAdd(&deg_in[d], 1.f); atomicAdd(&cnt_in[d], 1); }
}

__global__ void k_rs(float* deg){
    int i = blockIdx.x*256 + threadIdx.x;
    if (i >= 2*NN) return;
    deg[i] = rsqrtf(fmaxf(deg[i], 1.f));
}

// single-block exclusive scan of cnt_in -> row_start[0..NN]
__global__ __launch_bounds__(256) void k_scan(const int* __restrict__ cnt,
                                              int* __restrict__ row_start){
    __shared__ int part[256];
    int t = threadIdx.x;
    const int per = (NN + 255)/256;
    int lo = t*per, hi = min(lo+per, NN);
    int s = 0;
    for (int i = lo; i < hi; i++) s += cnt[i];
    part[t] = s; __syncthreads();
    for (int off = 1; off < 256; off <<= 1){
        int v = (t >= off) ? part[t-off] : 0;
        __syncthreads();
        part[t] += v;
        __syncthreads();
    }
    int base = part[t] - s;   // exclusive prefix
    for (int i = lo; i < hi; i++){ row_start[i] = base; base += cnt[i]; }
    if (t == 255) row_start[NN] = part[255];
}

// fill CSR: csr_src[row_start[d] + cursor[d]++] = s
__global__ void k_fill(const int* __restrict__ src, const int* __restrict__ dst,
                       const int* __restrict__ row_start, int* __restrict__ cursor,
                       int* __restrict__ csr_src){
    int e = blockIdx.x*256 + threadIdx.x;
    if (e >= EE) return;
    int s = src[e], d = dst[e];
    if ((unsigned)s >= NN || (unsigned)d >= NN) return;
    int pos = atomicAdd(&cursor[d], 1);
    csr_src[row_start[d] + pos] = s;
}

// hn[N,H] = h[N,IN] @ W_conv[IN,H]  (fp32 acc, bf16 staging out)
__global__ __launch_bounds__(256) void k_gemm1(const void* __restrict__ h,
                                               const void* __restrict__ W,
                                               const int* __restrict__ dcode,
                                               bf16* __restrict__ hn){
    int fh = dcode[0], fW = dcode[1];
    __shared__ float As[32][65];
    __shared__ float Bs[32][64];
    int tid = threadIdx.x;
    int row0 = blockIdx.y*64, col0 = blockIdx.x*64;
    int tx = tid & 15, ty = tid >> 4;
    float acc[4][4] = {};
    for (int k0 = 0; k0 < IND; k0 += 32){
        #pragma unroll
        for (int j = 0; j < 8; j++){
            int idx = tid + j*256;
            int m = idx >> 5, k = idx & 31;
            int r = row0 + m;
            As[k][m] = (r < NN) ? ldf3(h, (size_t)r*IND + k0 + k, fh) : 0.f;
            int kk = idx >> 6, n = idx & 63;
            Bs[kk][n] = ldf3(W, (size_t)(k0+kk)*HD + col0 + n, fW);
        }
        __syncthreads();
        #pragma unroll
        for (int k = 0; k < 32; k++){
            float a[4], b[4];
            #pragma unroll
            for (int i = 0; i < 4; i++) a[i] = As[k][ty*4+i];
            #pragma unroll
            for (int j = 0; j < 4; j++) b[j] = Bs[k][tx*4+j];
            #pragma unroll
            for (int i = 0; i < 4; i++)
                #pragma unroll
                for (int j = 0; j < 4; j++) acc[i][j] += a[i]*b[j];
        }
        __syncthreads();
    }
    #pragma unroll
    for (int i = 0; i < 4; i++){
        int r = row0 + ty*4 + i;
        if (r < NN){
            #pragma unroll
            for (int j = 0; j < 4; j++)
                hn[(size_t)r*HD + col0 + tx*4 + j] = __float2bfloat16(acc[i][j]);
        }
    }
}

// fused gather + epilogue: one wave per dst node.
// hr[n,:] = relu( (sum_{s in CSR[n]} rs_out[s]*hn[s,:]) * rs_in[n] + b_conv )
// gate[n] = hr[n,:].w_gate + b_gate
__global__ __launch_bounds__(256) void k_gather(const bf16* __restrict__ hn,
                                                const float* __restrict__ rs_out,
                                                const float* __restrict__ rs_in,
                                                const int* __restrict__ row_start,
                                                const int* __restrict__ csr_src,
                                                const void* __restrict__ b_conv,
                                                const void* __restrict__ w_gate,
                                                const void* __restrict__ b_gate,
                                                const int* __restrict__ dcode,
                                                float* __restrict__ hr,
                                                float* __restrict__ gate){
    int wave = threadIdx.x >> 6, lane = threadIdx.x & 63;
    int n = blockIdx.x*4 + wave;
    if (n >= NN) return;
    int lo = row_start[n], hi = row_start[n+1];
    float ax = 0.f, ay = 0.f, az = 0.f, aw = 0.f;
    for (int j = lo; j < hi; j++){
        int s = csr_src[j];
        float rs = rs_out[s];
        ushort4 u = ((const ushort4*)(hn + (size_t)s*HD))[lane];
        ax = fmaf(bits2f(u.x), rs, ax);
        ay = fmaf(bits2f(u.y), rs, ay);
        az = fmaf(bits2f(u.z), rs, az);
        aw = fmaf(bits2f(u.w), rs, aw);
    }
    int db = dcode[5], fg = dcode[2];
    float rsn = rs_in[n];
    int c = lane*4;
    ax = fmaxf(fmaf(ax, rsn, ldf3(b_conv, c+0, db)), 0.f);
    ay = fmaxf(fmaf(ay, rsn, ldf3(b_conv, c+1, db)), 0.f);
    az = fmaxf(fmaf(az, rsn, ldf3(b_conv, c+2, db)), 0.f);
    aw = fmaxf(fmaf(aw, rsn, ldf3(b_conv, c+3, db)), 0.f);
    float4 v; v.x = ax; v.y = ay; v.z = az; v.w = aw;
    ((float4*)(hr + (size_t)n*HD))[lane] = v;
    float g = ax*ldf3(w_gate, c+0, fg) + ay*ldf3(w_gate, c+1, fg)
            + az*ldf3(w_gate, c+2, fg) + aw*ldf3(w_gate, c+3, fg);
    #pragma unroll
    for (int off = 32; off; off >>= 1) g += __shfl_down(g, off);
    if (lane == 0) gate[n] = g + ldf3(b_gate, 0, db);
}

__global__ __launch_bounds__(256) void k_gmax(const int* __restrict__ gid,
                                              const float* __restrict__ gate,
                                              float* gmax, int* gstart, int* gend){
    int g = blockIdx.x, tid = threadIdx.x;
    float m = -INFINITY; int lo = NN, hi = -1;
    for (int n = tid; n < NN; n += 256){
        if (gid[n] == g){ float v = gate[n]; m = fmaxf(m, v); lo = min(lo, n); hi = max(hi, n); }
    }
    __shared__ float sm[256]; __shared__ int sl[256], sh[256];
    sm[tid] = m; sl[tid] = lo; sh[tid] = hi; __syncthreads();
    for (int s = 128; s; s >>= 1){
        if (tid < s){
            sm[tid] = fmaxf(sm[tid], sm[tid+s]);
            sl[tid] = min(sl[tid], sl[tid+s]);
            sh[tid] = max(sh[tid], sh[tid+s]);
        }
        __syncthreads();
    }
    if (tid == 0){ gmax[g] = sm[0]; gstart[g] = sl[0]; gend[g] = sh[0] + 1; }
}

__global__ void k_exps(const int* __restrict__ gid, float* __restrict__ gate,
                       const float* __restrict__ gmax, float* denom){
    int n = blockIdx.x*256 + threadIdx.x;
    if (n >= NN) return;
    int g = min(max(gid[n], 0), GG-1);
    float e = expf(fminf(gate[n] - gmax[g], 0.f));
    gate[n] = e;
    atomicAdd(&denom[g], e);
}

__global__ void k_att(const int* __restrict__ gid, float* __restrict__ gate,
                      const float* __restrict__ denom, float* __restrict__ out_att){
    int n = blockIdx.x*256 + threadIdx.x;
    if (n >= NN) return;
    int g = min(max(gid[n], 0), GG-1);
    float a = gate[n] / denom[g];
    gate[n] = a;
    out_att[n] = a;
}

__global__ __launch_bounds__(256) void k_hg(const float* __restrict__ att,
                                            const float* __restrict__ hr,
                                            const int* __restrict__ gstart,
                                            const int* __restrict__ gend,
                                            float* __restrict__ hg){
    int g = blockIdx.x >> 3, part = blockIdx.x & 7;
    int c = threadIdx.x;
    int s = gstart[g], en = gend[g];
    int len = en - s;
    if (len <= 0) return;
    int chunk = (len + 7) >> 3;
    int lo = s + part*chunk, hi = min(lo + chunk, en);
    if (lo >= hi) return;
    float acc = 0.f;
    for (int n = lo; n < hi; n++) acc += att[n] * hr[(size_t)n*HD + c];
    atomicAdd(&hg[g*HD + c], acc);
}

__global__ __launch_bounds__(256) void k_cls(const float* __restrict__ hg,
                                             const void* __restrict__ W1,
                                             const void* __restrict__ b1,
                                             const void* __restrict__ W2,
                                             const void* __restrict__ b2,
                                             const int* __restrict__ dcode,
                                             float* __restrict__ out0,
                                             float* __restrict__ out_hg){
    int f1 = dcode[3], f2 = dcode[4], db = dcode[5];
    int g = blockIdx.x, tid = threadIdx.x;
    __shared__ float hs[256];
    float hv = hg[g*HD + tid];
    hs[tid] = hv;
    out_hg[g*HD + tid] = hv;
    __syncthreads();
    float acc = ldf3(b1, tid, db);
    if (f1 == 1){
        const bf16* w = (const bf16*)W1;
        for (int k = 0; k < HD; k++) acc += hs[k]*b2f(w[(size_t)k*HD + tid]);
    } else if (f1 == 2){
        const __half* w = (const __half*)W1;
        for (int k = 0; k < HD; k++) acc += hs[k]*__half2float(w[(size_t)k*HD + tid]);
    } else {
        const float* w = (const float*)W1;
        for (int k = 0; k < HD; k++) acc += hs[k]*w[(size_t)k*HD + tid];
    }
    float p0 = acc * ldf3(W2, tid*CC + 0, f2);
    float p1 = acc * ldf3(W2, tid*CC + 1, f2);
    __shared__ float r0[256], r1[256];
    r0[tid] = p0; r1[tid] = p1; __syncthreads();
    for (int s = 128; s; s >>= 1){
        if (tid < s){ r0[tid] += r0[tid+s]; r1[tid] += r1[tid+s]; }
        __syncthreads();
    }
    if (tid == 0){
        out0[g*CC+0] = 1.f/(1.f + expf(-(r0[0] + ldf3(b2, 0, db))));
        out0[g*CC+1] = 1.f/(1.f + expf(-(r1[0] + ldf3(b2, 1, db))));
    }
}

extern "C" void kernel_launch(void* const* d_in, const int* in_sizes, int n_in,
                              void* d_out, int out_size, void* d_ws, size_t ws_size,
                              hipStream_t stream) {
    const void* h      = d_in[0];
    const void* src_r  = d_in[1];
    const void* dst_r  = d_in[2];
    const void* gid_r  = d_in[3];
    const void* W_conv = d_in[4];
    const void* b_conv = d_in[5];
    const void* w_gate = d_in[6];
    const void* b_gate = d_in[7];
    const void* W1     = d_in[8];
    const void* b1     = d_in[9];
    const void* W2     = d_in[10];
    const void* b2     = d_in[11];

    float* out     = (float*)d_out;      // fp32 output (established R10)
    float* out0    = out;                // [G,C]
    float* out_att = out + GG*CC;        // [N]
    float* out_hg  = out + GG*CC + NN;   // [G,H]

    char* w = (char*)d_ws;
    float* hr   = (float*)w;  w += (size_t)NN*HD*sizeof(float);
    bf16*  hn   = (bf16*)w;   w += (size_t)NN*HD*sizeof(bf16);
    float* deg  = (float*)w;  w += (size_t)2*NN*sizeof(float);
    float* deg_out = deg;
    float* deg_in  = deg + NN;
    float* gate = (float*)w;  w += (size_t)NN*sizeof(float);
    float* gmax = (float*)w;  w += GG*sizeof(float);
    float* denom= (float*)w;  w += GG*sizeof(float);
    float* hg   = (float*)w;  w += (size_t)GG*HD*sizeof(float);
    int* gstart = (int*)w;    w += GG*sizeof(int);
    int* gend   = (int*)w;    w += GG*sizeof(int);
    int* dcode  = (int*)w;    w += 8*sizeof(int);
    int* icode  = (int*)w;    w += 8*sizeof(int);
    int* src_i  = (int*)w;    w += (size_t)EE*sizeof(int);
    int* dst_i  = (int*)w;    w += (size_t)EE*sizeof(int);
    int* gid_i  = (int*)w;    w += (size_t)NN*sizeof(int);
    int* cnt_in = (int*)w;    w += (size_t)NN*sizeof(int);
    int* cursor = (int*)w;    w += (size_t)NN*sizeof(int);
    int* rowst  = (int*)w;    w += (size_t)(NN+1)*sizeof(int);
    int* csr    = (int*)w;    w += (size_t)EE*sizeof(int);

    k_dtype<<<1, 64, 0, stream>>>((const unsigned short*)h, (const unsigned short*)W_conv,
                                  (const unsigned short*)w_gate, (const unsigned short*)W1,
                                  (const unsigned short*)W2, (const unsigned short*)b_conv,
                                  dcode);
    k_idet4<<<1, 64, 0, stream>>>(src_r, EE, NN, icode+0);
    k_idet4<<<1, 64, 0, stream>>>(dst_r, EE, NN, icode+1);
    k_idet4<<<1, 64, 0, stream>>>(gid_r, NN, GG, icode+2);
    k_idecode4<<<(EE+255)/256, 256, 0, stream>>>(src_r, EE, icode+0, src_i);
    k_idecode4<<<(EE+255)/256, 256, 0, stream>>>(dst_r, EE, icode+1, dst_i);
    k_idecode4<<<(NN+255)/256, 256, 0, stream>>>(gid_r, NN, icode+2, gid_i);

    hipMemsetAsync(deg, 0, (size_t)2*NN*sizeof(float), stream);
    hipMemsetAsync(denom, 0, (size_t)(GG + GG*HD)*sizeof(float), stream);
    hipMemsetAsync(cnt_in, 0, (size_t)2*NN*sizeof(int), stream);  // cnt_in + cursor
    k_init<<<1, 64, 0, stream>>>(gmax, gstart, gend);

    k_deg<<<(EE+255)/256, 256, 0, stream>>>(src_i, dst_i, deg_out, deg_in, cnt_in);
    k_rs<<<(2*NN+255)/256, 256, 0, stream>>>(deg);
    k_scan<<<1, 256, 0, stream>>>(cnt_in, rowst);
    k_fill<<<(EE+255)/256, 256, 0, stream>>>(src_i, dst_i, rowst, cursor, csr);

    dim3 g1(HD/64, (NN+63)/64);
    k_gemm1<<<g1, 256, 0, stream>>>(h, W_conv, dcode, hn);

    k_gather<<<(NN+3)/4, 256, 0, stream>>>(hn, deg_out, deg_in, rowst, csr,
                                           b_conv, w_gate, b_gate, dcode, hr, gate);

    k_gmax<<<GG, 256, 0, stream>>>(gid_i, gate, gmax, gstart, gend);
    k_exps<<<(NN+255)/256, 256, 0, stream>>>(gid_i, gate, gmax, denom);
    k_att<<<(NN+255)/256, 256, 0, stream>>>(gid_i, gate, denom, out_att);
    k_hg<<<GG*8, 256, 0, stream>>>(gate, hr, gstart, gend, hg);
    k_cls<<<GG, 256, 0, stream>>>(hg, W1, b1, W2, b2, dcode, out0, out_hg);
}

// Round 12
// 407.160 us; speedup vs baseline: 3.5475x; 1.1861x over previous
//
#include <hip/hip_runtime.h>
#include <hip/hip_bf16.h>
#include <hip/hip_fp16.h>
#include <math.h>

#define NN 20000
#define EE 320000
#define GG 64
#define IND 256
#define HD 256
#define CC 2

typedef __hip_bfloat16 bf16;
typedef __attribute__((ext_vector_type(8))) short short8;
typedef __attribute__((ext_vector_type(4))) float f32x4;

__device__ __forceinline__ float b2f(bf16 x){ return __bfloat162float(x); }
__device__ __forceinline__ float bits2f(unsigned short b){
    union{ float f; unsigned u; } v; v.u = ((unsigned)b) << 16; return v.f;
}
// float load by code: 0=fp32, 1=bf16, 2=fp16
__device__ __forceinline__ float ldf3(const void* p, size_t i, int c){
    if (c == 1) return b2f(((const bf16*)p)[i]);
    if (c == 2) return __half2float(((const __half*)p)[i]);
    return ((const float*)p)[i];
}
__device__ __forceinline__ int idec(const void* p, int i, int c){
    if (c == 1) return (int)(((const long long*)p)[i]);
    if (c == 2) return (int)(((const float*)p)[i]);
    if (c == 3) return (int)__half2float(((const __half*)p)[i]);
    return ((const int*)p)[i];
}

// ---- float dtype detection (insurance; expected all fp32) ----
__global__ void k_dtype(const unsigned short* h, const unsigned short* Wc,
                        const unsigned short* wg, const unsigned short* W1,
                        const unsigned short* W2, const unsigned short* bc,
                        int* dcode){
    int t = threadIdx.x; if (t >= 6) return;
    const unsigned short* p = t==0?h:t==1?Wc:t==2?wg:t==3?W1:t==4?W2:bc;
    int cb = 0, cf = 0, nz = 0;
    for (int i = 0; i < 128; i += 2){
        unsigned u = p[i];
        nz += (u != 0);
        int e8 = (u >> 7) & 0xFF;
        int e5 = (u >> 10) & 0x1F;
        cb += (e8 >= 100 && e8 <= 141);
        cf += (e5 >= 4 && e5 <= 22);
    }
    dcode[t] = (nz < 8) ? 0 : (cb >= 60) ? 1 : ((cf >= 60) ? 2 : 0);
}

// ---- merged int format detection: block 0=src, 1=dst, 2=gid ----
__global__ void k_idet(const void* src, const void* dst, const void* gid, int* code){
    if (threadIdx.x != 0) return;
    const void* buf = (blockIdx.x == 0) ? src : (blockIdx.x == 1) ? dst : gid;
    int n     = (blockIdx.x == 2) ? NN : EE;
    int bound = (blockIdx.x == 2) ? GG : NN;
    int ok64 = 1, ok32 = 1, okf32 = 1, okf16 = 1;
    const long long* p64 = (const long long*)buf;
    for (int i = 0; i < 64; i++){
        long long v = p64[n/8 + i];
        if (v < 0 || v >= (long long)bound) ok64 = 0;
    }
    const int* p32 = (const int*)buf;
    const unsigned* pu = (const unsigned*)buf;
    for (int i = 0; i < 64; i++){
        int v = p32[n/4 + i];
        if (v < 0 || v >= bound) ok32 = 0;
        float f = __uint_as_float(pu[n/4 + i]);
        if (!(f >= 0.f && f < (float)bound)) okf32 = 0;
    }
    const __half* ph = (const __half*)buf;
    for (int i = 0; i < 64; i++){
        float f = __half2float(ph[n/2 + i]);
        if (!(f >= 0.f && f < (float)bound)) okf16 = 0;
    }
    code[blockIdx.x] = ok64 ? 1 : (ok32 ? 0 : (okf32 ? 2 : (okf16 ? 3 : 0)));
}

__global__ void k_init(float* gmax, int* gstart, int* gend){
    int g = threadIdx.x;
    if (g < GG){ gmax[g] = -INFINITY; gstart[g] = NN; gend[g] = 0; }
}

// fused decode (src,dst,gid) + degree counting
__global__ void k_prep(const void* src_r, const void* dst_r, const void* gid_r,
                       const int* __restrict__ icode,
                       int* __restrict__ src_i, int* __restrict__ dst_i,
                       int* __restrict__ gid_i,
                       float* deg_out, float* deg_in, int* cnt_in){
    int i = blockIdx.x*256 + threadIdx.x;
    if (i < NN) gid_i[i] = idec(gid_r, i, icode[2]);
    if (i >= EE) return;
    int s = idec(src_r, i, icode[0]);
    int d = idec(dst_r, i, icode[1]);
    src_i[i] = s; dst_i[i] = d;
    if ((unsigned)s < NN) atomicAdd(&deg_out[s], 1.f);
    if ((unsigned)d < NN){ atomicAdd(&deg_in[d], 1.f); atomicAdd(&cnt_in[d], 1); }
}

__global__ void k_rs(float* deg){
    int i = blockIdx.x*256 + threadIdx.x;
    if (i >= 2*NN) return;
    deg[i] = rsqrtf(fmaxf(deg[i], 1.f));
}

// single-block exclusive scan of cnt_in -> row_start[0..NN]
__global__ __launch_bounds__(256) void k_scan(const int* __restrict__ cnt,
                                              int* __restrict__ row_start){
    __shared__ int part[256];
    int t = threadIdx.x;
    const int per = (NN + 255)/256;
    int lo = t*per, hi = min(lo+per, NN);
    int s = 0;
    for (int i = lo; i < hi; i++) s += cnt[i];
    part[t] = s; __syncthreads();
    for (int off = 1; off < 256; off <<= 1){
        int v = (t >= off) ? part[t-off] : 0;
        __syncthreads();
        part[t] += v;
        __syncthreads();
    }
    int base = part[t] - s;
    for (int i = lo; i < hi; i++){ row_start[i] = base; base += cnt[i]; }
    if (t == 255) row_start[NN] = part[255];
}

__global__ void k_fill(const int* __restrict__ src, const int* __restrict__ dst,
                       const int* __restrict__ row_start, int* __restrict__ cursor,
                       int* __restrict__ csr_src){
    int e = blockIdx.x*256 + threadIdx.x;
    if (e >= EE) return;
    int s = src[e], d = dst[e];
    if ((unsigned)s >= NN || (unsigned)d >= NN) return;
    int pos = atomicAdd(&cursor[d], 1);
    csr_src[row_start[d] + pos] = s;
}

// W_conv[IN][HD] fp32 -> Wb[n][k] bf16 (fragment-friendly transpose)
__global__ void k_wprep(const void* __restrict__ W, const int* __restrict__ dcode,
                        bf16* __restrict__ Wb){
    int k = blockIdx.x;          // 0..IND-1
    int n = threadIdx.x;         // 0..HD-1
    Wb[(size_t)n*IND + k] = __float2bfloat16(ldf3(W, (size_t)k*HD + n, dcode[1]));
}

// MFMA GEMM: hn[N,HD] = h[N,IND] @ W_conv  (bf16 in, fp32 acc, bf16 out)
// block = 64 rows x 256 cols (4 waves, wave w owns cols [64w,64w+64))
__global__ __launch_bounds__(256) void k_gemm1m(const void* __restrict__ h,
                                                const bf16* __restrict__ Wb,
                                                const int* __restrict__ dcode,
                                                bf16* __restrict__ hn){
    int fh = dcode[0];
    __shared__ __align__(16) bf16 Al[64][40];   // 80B row stride, 16B aligned frags
    int tid = threadIdx.x;
    int wave = tid >> 6, lane = tid & 63;
    int q = lane >> 4, mr = lane & 15;
    int row0 = blockIdx.x * 64;
    int ncol0 = wave * 64;
    f32x4 acc[4][4] = {};   // [mtile][ntile]
    for (int k0 = 0; k0 < IND; k0 += 32){
        // stage A: 64x32 fp32 -> bf16 LDS
        #pragma unroll
        for (int j = 0; j < 8; j++){
            int idx = tid + j*256;
            int m = idx >> 5, k = idx & 31;
            int r = row0 + m;
            float v = (r < NN) ? ldf3(h, (size_t)r*IND + k0 + k, fh) : 0.f;
            Al[m][k] = __float2bfloat16(v);
        }
        __syncthreads();
        short8 a[4], b[4];
        #pragma unroll
        for (int mi = 0; mi < 4; mi++)
            a[mi] = *reinterpret_cast<const short8*>(&Al[mi*16 + mr][q*8]);
        #pragma unroll
        for (int ni = 0; ni < 4; ni++){
            const bf16* bp = Wb + (size_t)(ncol0 + ni*16 + mr)*IND + k0 + q*8;
            b[ni] = *reinterpret_cast<const short8*>(bp);
        }
        #pragma unroll
        for (int mi = 0; mi < 4; mi++)
            #pragma unroll
            for (int ni = 0; ni < 4; ni++)
                acc[mi][ni] = __builtin_amdgcn_mfma_f32_16x16x32_bf16(
                                  a[mi], b[ni], acc[mi][ni], 0, 0, 0);
        __syncthreads();
    }
    // D: row = q*4 + r, col = mr (per 16x16 tile)
    #pragma unroll
    for (int mi = 0; mi < 4; mi++){
        int rowb = row0 + mi*16 + q*4;
        #pragma unroll
        for (int r = 0; r < 4; r++){
            int row = rowb + r;
            if (row < NN){
                #pragma unroll
                for (int ni = 0; ni < 4; ni++)
                    hn[(size_t)row*HD + ncol0 + ni*16 + mr] = __float2bfloat16(acc[mi][ni][r]);
            }
        }
    }
}

// fused gather + epilogue: one wave per dst node.
__global__ __launch_bounds__(256) void k_gather(const bf16* __restrict__ hn,
                                                const float* __restrict__ rs_out,
                                                const float* __restrict__ rs_in,
                                                const int* __restrict__ row_start,
                                                const int* __restrict__ csr_src,
                                                const void* __restrict__ b_conv,
                                                const void* __restrict__ w_gate,
                                                const void* __restrict__ b_gate,
                                                const int* __restrict__ dcode,
                                                float* __restrict__ hr,
                                                float* __restrict__ gate){
    int wave = threadIdx.x >> 6, lane = threadIdx.x & 63;
    int n = blockIdx.x*4 + wave;
    if (n >= NN) return;
    int lo = row_start[n], hi = row_start[n+1];
    float ax = 0.f, ay = 0.f, az = 0.f, aw = 0.f;
    for (int j = lo; j < hi; j++){
        int s = csr_src[j];
        float rs = rs_out[s];
        ushort4 u = ((const ushort4*)(hn + (size_t)s*HD))[lane];
        ax = fmaf(bits2f(u.x), rs, ax);
        ay = fmaf(bits2f(u.y), rs, ay);
        az = fmaf(bits2f(u.z), rs, az);
        aw = fmaf(bits2f(u.w), rs, aw);
    }
    int db = dcode[5], fg = dcode[2];
    float rsn = rs_in[n];
    int c = lane*4;
    ax = fmaxf(fmaf(ax, rsn, ldf3(b_conv, c+0, db)), 0.f);
    ay = fmaxf(fmaf(ay, rsn, ldf3(b_conv, c+1, db)), 0.f);
    az = fmaxf(fmaf(az, rsn, ldf3(b_conv, c+2, db)), 0.f);
    aw = fmaxf(fmaf(aw, rsn, ldf3(b_conv, c+3, db)), 0.f);
    float4 v; v.x = ax; v.y = ay; v.z = az; v.w = aw;
    ((float4*)(hr + (size_t)n*HD))[lane] = v;
    float g = ax*ldf3(w_gate, c+0, fg) + ay*ldf3(w_gate, c+1, fg)
            + az*ldf3(w_gate, c+2, fg) + aw*ldf3(w_gate, c+3, fg);
    #pragma unroll
    for (int off = 32; off; off >>= 1) g += __shfl_down(g, off);
    if (lane == 0) gate[n] = g + ldf3(b_gate, 0, db);
}

__global__ __launch_bounds__(256) void k_gmax(const int* __restrict__ gid,
                                              const float* __restrict__ gate,
                                              float* gmax, int* gstart, int* gend){
    int g = blockIdx.x, tid = threadIdx.x;
    float m = -INFINITY; int lo = NN, hi = -1;
    for (int n = tid; n < NN; n += 256){
        if (gid[n] == g){ float v = gate[n]; m = fmaxf(m, v); lo = min(lo, n); hi = max(hi, n); }
    }
    __shared__ float sm[256]; __shared__ int sl[256], sh[256];
    sm[tid] = m; sl[tid] = lo; sh[tid] = hi; __syncthreads();
    for (int s = 128; s; s >>= 1){
        if (tid < s){
            sm[tid] = fmaxf(sm[tid], sm[tid+s]);
            sl[tid] = min(sl[tid], sl[tid+s]);
            sh[tid] = max(sh[tid], sh[tid+s]);
        }
        __syncthreads();
    }
    if (tid == 0){ gmax[g] = sm[0]; gstart[g] = sl[0]; gend[g] = sh[0] + 1; }
}

__global__ void k_exps(const int* __restrict__ gid, float* __restrict__ gate,
                       const float* __restrict__ gmax, float* denom){
    int n = blockIdx.x*256 + threadIdx.x;
    if (n >= NN) return;
    int g = min(max(gid[n], 0), GG-1);
    float e = expf(fminf(gate[n] - gmax[g], 0.f));
    gate[n] = e;
    atomicAdd(&denom[g], e);
}

__global__ void k_att(const int* __restrict__ gid, float* __restrict__ gate,
                      const float* __restrict__ denom, float* __restrict__ out_att){
    int n = blockIdx.x*256 + threadIdx.x;
    if (n >= NN) return;
    int g = min(max(gid[n], 0), GG-1);
    float a = gate[n] / denom[g];
    gate[n] = a;
    out_att[n] = a;
}

__global__ __launch_bounds__(256) void k_hg(const float* __restrict__ att,
                                            const float* __restrict__ hr,
                                            const int* __restrict__ gstart,
                                            const int* __restrict__ gend,
                                            float* __restrict__ hg){
    int g = blockIdx.x >> 3, part = blockIdx.x & 7;
    int c = threadIdx.x;
    int s = gstart[g], en = gend[g];
    int len = en - s;
    if (len <= 0) return;
    int chunk = (len + 7) >> 3;
    int lo = s + part*chunk, hi = min(lo + chunk, en);
    if (lo >= hi) return;
    float acc = 0.f;
    for (int n = lo; n < hi; n++) acc += att[n] * hr[(size_t)n*HD + c];
    atomicAdd(&hg[g*HD + c], acc);
}

__global__ __launch_bounds__(256) void k_cls(const float* __restrict__ hg,
                                             const void* __restrict__ W1,
                                             const void* __restrict__ b1,
                                             const void* __restrict__ W2,
                                             const void* __restrict__ b2,
                                             const int* __restrict__ dcode,
                                             float* __restrict__ out0,
                                             float* __restrict__ out_hg){
    int f1 = dcode[3], f2 = dcode[4], db = dcode[5];
    int g = blockIdx.x, tid = threadIdx.x;
    __shared__ float hs[256];
    float hv = hg[g*HD + tid];
    hs[tid] = hv;
    out_hg[g*HD + tid] = hv;
    __syncthreads();
    float acc = ldf3(b1, tid, db);
    if (f1 == 1){
        const bf16* w = (const bf16*)W1;
        for (int k = 0; k < HD; k++) acc += hs[k]*b2f(w[(size_t)k*HD + tid]);
    } else if (f1 == 2){
        const __half* w = (const __half*)W1;
        for (int k = 0; k < HD; k++) acc += hs[k]*__half2float(w[(size_t)k*HD + tid]);
    } else {
        const float* w = (const float*)W1;
        for (int k = 0; k < HD; k++) acc += hs[k]*w[(size_t)k*HD + tid];
    }
    float p0 = acc * ldf3(W2, tid*CC + 0, f2);
    float p1 = acc * ldf3(W2, tid*CC + 1, f2);
    __shared__ float r0[256], r1[256];
    r0[tid] = p0; r1[tid] = p1; __syncthreads();
    for (int s = 128; s; s >>= 1){
        if (tid < s){ r0[tid] += r0[tid+s]; r1[tid] += r1[tid+s]; }
        __syncthreads();
    }
    if (tid == 0){
        out0[g*CC+0] = 1.f/(1.f + expf(-(r0[0] + ldf3(b2, 0, db))));
        out0[g*CC+1] = 1.f/(1.f + expf(-(r1[0] + ldf3(b2, 1, db))));
    }
}

extern "C" void kernel_launch(void* const* d_in, const int* in_sizes, int n_in,
                              void* d_out, int out_size, void* d_ws, size_t ws_size,
                              hipStream_t stream) {
    const void* h      = d_in[0];
    const void* src_r  = d_in[1];
    const void* dst_r  = d_in[2];
    const void* gid_r  = d_in[3];
    const void* W_conv = d_in[4];
    const void* b_conv = d_in[5];
    const void* w_gate = d_in[6];
    const void* b_gate = d_in[7];
    const void* W1     = d_in[8];
    const void* b1     = d_in[9];
    const void* W2     = d_in[10];
    const void* b2     = d_in[11];

    float* out     = (float*)d_out;      // fp32 output (established R10)
    float* out0    = out;                // [G,C]
    float* out_att = out + GG*CC;        // [N]
    float* out_hg  = out + GG*CC + NN;   // [G,H]

    char* w = (char*)d_ws;
    float* hr   = (float*)w;  w += (size_t)NN*HD*sizeof(float);
    bf16*  hn   = (bf16*)w;   w += (size_t)NN*HD*sizeof(bf16);
    bf16*  Wb   = (bf16*)w;   w += (size_t)IND*HD*sizeof(bf16);
    float* deg  = (float*)w;  w += (size_t)2*NN*sizeof(float);
    float* deg_out = deg;
    float* deg_in  = deg + NN;
    float* gate = (float*)w;  w += (size_t)NN*sizeof(float);
    float* gmax = (float*)w;  w += GG*sizeof(float);
    float* denom= (float*)w;  w += GG*sizeof(float);
    float* hg   = (float*)w;  w += (size_t)GG*HD*sizeof(float);
    int* gstart = (int*)w;    w += GG*sizeof(int);
    int* gend   = (int*)w;    w += GG*sizeof(int);
    int* dcode  = (int*)w;    w += 8*sizeof(int);
    int* icode  = (int*)w;    w += 8*sizeof(int);
    int* src_i  = (int*)w;    w += (size_t)EE*sizeof(int);
    int* dst_i  = (int*)w;    w += (size_t)EE*sizeof(int);
    int* gid_i  = (int*)w;    w += (size_t)NN*sizeof(int);
    int* cnt_in = (int*)w;    w += (size_t)NN*sizeof(int);
    int* cursor = (int*)w;    w += (size_t)NN*sizeof(int);
    int* rowst  = (int*)w;    w += (size_t)(NN+1)*sizeof(int);
    int* csr    = (int*)w;    w += (size_t)EE*sizeof(int);

    k_dtype<<<1, 64, 0, stream>>>((const unsigned short*)h, (const unsigned short*)W_conv,
                                  (const unsigned short*)w_gate, (const unsigned short*)W1,
                                  (const unsigned short*)W2, (const unsigned short*)b_conv,
                                  dcode);
    k_idet<<<3, 64, 0, stream>>>(src_r, dst_r, gid_r, icode);

    hipMemsetAsync(deg, 0, (size_t)2*NN*sizeof(float), stream);
    hipMemsetAsync(denom, 0, (size_t)(GG + GG*HD)*sizeof(float), stream);
    hipMemsetAsync(cnt_in, 0, (size_t)2*NN*sizeof(int), stream);  // cnt_in + cursor
    k_init<<<1, 64, 0, stream>>>(gmax, gstart, gend);

    k_prep<<<(EE+255)/256, 256, 0, stream>>>(src_r, dst_r, gid_r, icode,
                                             src_i, dst_i, gid_i,
                                             deg_out, deg_in, cnt_in);
    k_rs<<<(2*NN+255)/256, 256, 0, stream>>>(deg);
    k_scan<<<1, 256, 0, stream>>>(cnt_in, rowst);
    k_fill<<<(EE+255)/256, 256, 0, stream>>>(src_i, dst_i, rowst, cursor, csr);

    k_wprep<<<IND, HD, 0, stream>>>(W_conv, dcode, Wb);
    k_gemm1m<<<(NN+63)/64, 256, 0, stream>>>(h, Wb, dcode, hn);

    k_gather<<<(NN+3)/4, 256, 0, stream>>>(hn, deg_out, deg_in, rowst, csr,
                                           b_conv, w_gate, b_gate, dcode, hr, gate);

    k_gmax<<<GG, 256, 0, stream>>>(gid_i, gate, gmax, gstart, gend);
    k_exps<<<(NN+255)/256, 256, 0, stream>>>(gid_i, gate, gmax, denom);
    k_att<<<(NN+255)/256, 256, 0, stream>>>(gid_i, gate, denom, out_att);
    k_hg<<<GG*8, 256, 0, stream>>>(gate, hr, gstart, gend, hg);
    k_cls<<<GG, 256, 0, stream>>>(hg, W1, b1, W2, b2, dcode, out0, out_hg);
}

// Round 13
// 293.014 us; speedup vs baseline: 4.9295x; 1.3896x over previous
//
#include <hip/hip_runtime.h>
#include <hip/hip_bf16.h>
#include <hip/hip_fp16.h>
#include <math.h>

#define NN 20000
#define EE 320000
#define GG 64
#define IND 256
#define HD 256
#define CC 2

typedef __hip_bfloat16 bf16;
typedef __attribute__((ext_vector_type(8))) short short8;
typedef __attribute__((ext_vector_type(4))) float f32x4;

__device__ __forceinline__ float b2f(bf16 x){ return __bfloat162float(x); }
__device__ __forceinline__ float bits2f(unsigned short b){
    union{ float f; unsigned u; } v; v.u = ((unsigned)b) << 16; return v.f;
}
// float load by code: 0=fp32, 1=bf16, 2=fp16
__device__ __forceinline__ float ldf3(const void* p, size_t i, int c){
    if (c == 1) return b2f(((const bf16*)p)[i]);
    if (c == 2) return __half2float(((const __half*)p)[i]);
    return ((const float*)p)[i];
}
__device__ __forceinline__ int idec(const void* p, int i, int c){
    if (c == 1) return (int)(((const long long*)p)[i]);
    if (c == 2) return (int)(((const float*)p)[i]);
    if (c == 3) return (int)__half2float(((const __half*)p)[i]);
    return ((const int*)p)[i];
}

// ---- float dtype detection (insurance; expected all fp32) ----
__global__ void k_dtype(const unsigned short* h, const unsigned short* Wc,
                        const unsigned short* wg, const unsigned short* W1,
                        const unsigned short* W2, const unsigned short* bc,
                        int* dcode){
    int t = threadIdx.x; if (t >= 6) return;
    const unsigned short* p = t==0?h:t==1?Wc:t==2?wg:t==3?W1:t==4?W2:bc;
    int cb = 0, cf = 0, nz = 0;
    for (int i = 0; i < 128; i += 2){
        unsigned u = p[i];
        nz += (u != 0);
        int e8 = (u >> 7) & 0xFF;
        int e5 = (u >> 10) & 0x1F;
        cb += (e8 >= 100 && e8 <= 141);
        cf += (e5 >= 4 && e5 <= 22);
    }
    dcode[t] = (nz < 8) ? 0 : (cb >= 60) ? 1 : ((cf >= 60) ? 2 : 0);
}

// ---- merged int format detection: block 0=src, 1=dst, 2=gid ----
__global__ void k_idet(const void* src, const void* dst, const void* gid, int* code){
    if (threadIdx.x != 0) return;
    const void* buf = (blockIdx.x == 0) ? src : (blockIdx.x == 1) ? dst : gid;
    int n     = (blockIdx.x == 2) ? NN : EE;
    int bound = (blockIdx.x == 2) ? GG : NN;
    int ok64 = 1, ok32 = 1, okf32 = 1, okf16 = 1;
    const long long* p64 = (const long long*)buf;
    for (int i = 0; i < 64; i++){
        long long v = p64[n/8 + i];
        if (v < 0 || v >= (long long)bound) ok64 = 0;
    }
    const int* p32 = (const int*)buf;
    const unsigned* pu = (const unsigned*)buf;
    for (int i = 0; i < 64; i++){
        int v = p32[n/4 + i];
        if (v < 0 || v >= bound) ok32 = 0;
        float f = __uint_as_float(pu[n/4 + i]);
        if (!(f >= 0.f && f < (float)bound)) okf32 = 0;
    }
    const __half* ph = (const __half*)buf;
    for (int i = 0; i < 64; i++){
        float f = __half2float(ph[n/2 + i]);
        if (!(f >= 0.f && f < (float)bound)) okf16 = 0;
    }
    code[blockIdx.x] = ok64 ? 1 : (ok32 ? 0 : (okf32 ? 2 : (okf16 ? 3 : 0)));
}

// fused decode (src,dst,gid) + int degree counting
__global__ void k_prep(const void* src_r, const void* dst_r, const void* gid_r,
                       const int* __restrict__ icode,
                       int* __restrict__ src_i, int* __restrict__ dst_i,
                       int* __restrict__ gid_i,
                       int* cnt_out, int* cnt_in){
    int i = blockIdx.x*256 + threadIdx.x;
    if (i < NN) gid_i[i] = idec(gid_r, i, icode[2]);
    if (i >= EE) return;
    int s = idec(src_r, i, icode[0]);
    int d = idec(dst_r, i, icode[1]);
    src_i[i] = s; dst_i[i] = d;
    if ((unsigned)s < NN) atomicAdd(&cnt_out[s], 1);
    if ((unsigned)d < NN) atomicAdd(&cnt_in[d], 1);
}

// rs_out/rs_in from int counts
__global__ void k_rs(const int* __restrict__ cnt_out, const int* __restrict__ cnt_in,
                     float* rs_out, float* rs_in){
    int i = blockIdx.x*256 + threadIdx.x;
    if (i >= NN) return;
    rs_out[i] = rsqrtf(fmaxf((float)cnt_out[i], 1.f));
    rs_in[i]  = rsqrtf(fmaxf((float)cnt_in[i], 1.f));
}

// single-block exclusive scan of cnt_in -> row_start[0..NN]
__global__ __launch_bounds__(256) void k_scan(const int* __restrict__ cnt,
                                              int* __restrict__ row_start){
    __shared__ int part[256];
    int t = threadIdx.x;
    const int per = (NN + 255)/256;
    int lo = t*per, hi = min(lo+per, NN);
    int s = 0;
    for (int i = lo; i < hi; i++) s += cnt[i];
    part[t] = s; __syncthreads();
    for (int off = 1; off < 256; off <<= 1){
        int v = (t >= off) ? part[t-off] : 0;
        __syncthreads();
        part[t] += v;
        __syncthreads();
    }
    int base = part[t] - s;
    for (int i = lo; i < hi; i++){ row_start[i] = base; base += cnt[i]; }
    if (t == 255) row_start[NN] = part[255];
}

__global__ void k_fill(const int* __restrict__ src, const int* __restrict__ dst,
                       const int* __restrict__ row_start, int* __restrict__ cursor,
                       int* __restrict__ csr_src){
    int e = blockIdx.x*256 + threadIdx.x;
    if (e >= EE) return;
    int s = src[e], d = dst[e];
    if ((unsigned)s >= NN || (unsigned)d >= NN) return;
    int pos = atomicAdd(&cursor[d], 1);
    csr_src[row_start[d] + pos] = s;
}

// per-graph node ranges via binary search in sorted gid
__global__ void k_lb(const int* __restrict__ gid, int* gstart, int* gend){
    __shared__ int ls[GG+1];
    int t = threadIdx.x;
    if (t <= GG){
        int lo = 0, hi = NN;           // lower_bound(t)
        while (lo < hi){
            int mid = (lo + hi) >> 1;
            if (gid[mid] < t) lo = mid + 1; else hi = mid;
        }
        ls[t] = lo;
    }
    __syncthreads();
    if (t < GG){ gstart[t] = ls[t]; gend[t] = ls[t+1]; }
}

// segment softmax: one block per graph; no atomics
__global__ __launch_bounds__(256) void k_soft(const int* __restrict__ gstart,
                                              const int* __restrict__ gend,
                                              float* __restrict__ gate,
                                              float* __restrict__ out_att){
    int g = blockIdx.x, t = threadIdx.x;
    int lo = gstart[g], hi = gend[g];
    if (lo >= hi) return;
    __shared__ float sm[256];
    float m = -INFINITY;
    for (int n = lo + t; n < hi; n += 256) m = fmaxf(m, gate[n]);
    sm[t] = m; __syncthreads();
    for (int s = 128; s; s >>= 1){ if (t < s) sm[t] = fmaxf(sm[t], sm[t+s]); __syncthreads(); }
    m = sm[0]; __syncthreads();
    float acc = 0.f;
    for (int n = lo + t; n < hi; n += 256){
        float e = expf(gate[n] - m);
        gate[n] = e;
        acc += e;
    }
    sm[t] = acc; __syncthreads();
    for (int s = 128; s; s >>= 1){ if (t < s) sm[t] += sm[t+s]; __syncthreads(); }
    float inv = 1.f / sm[0];
    for (int n = lo + t; n < hi; n += 256){
        float a = gate[n] * inv;
        gate[n] = a;
        out_att[n] = a;
    }
}

// W_conv[IN][HD] fp32 -> Wb[n][k] bf16 (fragment-friendly transpose)
__global__ void k_wprep(const void* __restrict__ W, const int* __restrict__ dcode,
                        bf16* __restrict__ Wb){
    int k = blockIdx.x;
    int n = threadIdx.x;
    Wb[(size_t)n*IND + k] = __float2bfloat16(ldf3(W, (size_t)k*HD + n, dcode[1]));
}

// MFMA GEMM: hn[N,HD] = h[N,IND] @ W_conv  (bf16 in, fp32 acc, bf16 out)
__global__ __launch_bounds__(256) void k_gemm1m(const void* __restrict__ h,
                                                const bf16* __restrict__ Wb,
                                                const int* __restrict__ dcode,
                                                bf16* __restrict__ hn){
    int fh = dcode[0];
    __shared__ __align__(16) bf16 Al[64][40];
    int tid = threadIdx.x;
    int wave = tid >> 6, lane = tid & 63;
    int q = lane >> 4, mr = lane & 15;
    int row0 = blockIdx.x * 64;
    int ncol0 = wave * 64;
    f32x4 acc[4][4] = {};
    for (int k0 = 0; k0 < IND; k0 += 32){
        #pragma unroll
        for (int j = 0; j < 8; j++){
            int idx = tid + j*256;
            int m = idx >> 5, k = idx & 31;
            int r = row0 + m;
            float v = (r < NN) ? ldf3(h, (size_t)r*IND + k0 + k, fh) : 0.f;
            Al[m][k] = __float2bfloat16(v);
        }
        __syncthreads();
        short8 a[4], b[4];
        #pragma unroll
        for (int mi = 0; mi < 4; mi++)
            a[mi] = *reinterpret_cast<const short8*>(&Al[mi*16 + mr][q*8]);
        #pragma unroll
        for (int ni = 0; ni < 4; ni++){
            const bf16* bp = Wb + (size_t)(ncol0 + ni*16 + mr)*IND + k0 + q*8;
            b[ni] = *reinterpret_cast<const short8*>(bp);
        }
        #pragma unroll
        for (int mi = 0; mi < 4; mi++)
            #pragma unroll
            for (int ni = 0; ni < 4; ni++)
                acc[mi][ni] = __builtin_amdgcn_mfma_f32_16x16x32_bf16(
                                  a[mi], b[ni], acc[mi][ni], 0, 0, 0);
        __syncthreads();
    }
    #pragma unroll
    for (int mi = 0; mi < 4; mi++){
        int rowb = row0 + mi*16 + q*4;
        #pragma unroll
        for (int r = 0; r < 4; r++){
            int row = rowb + r;
            if (row < NN){
                #pragma unroll
                for (int ni = 0; ni < 4; ni++)
                    hn[(size_t)row*HD + ncol0 + ni*16 + mr] = __float2bfloat16(acc[mi][ni][r]);
            }
        }
    }
}

// fused gather + epilogue: one wave per dst node.
__global__ __launch_bounds__(256) void k_gather(const bf16* __restrict__ hn,
                                                const float* __restrict__ rs_out,
                                                const float* __restrict__ rs_in,
                                                const int* __restrict__ row_start,
                                                const int* __restrict__ csr_src,
                                                const void* __restrict__ b_conv,
                                                const void* __restrict__ w_gate,
                                                const void* __restrict__ b_gate,
                                                const int* __restrict__ dcode,
                                                float* __restrict__ hr,
                                                float* __restrict__ gate){
    int wave = threadIdx.x >> 6, lane = threadIdx.x & 63;
    int n = blockIdx.x*4 + wave;
    if (n >= NN) return;
    int lo = row_start[n], hi = row_start[n+1];
    float ax = 0.f, ay = 0.f, az = 0.f, aw = 0.f;
    for (int j = lo; j < hi; j++){
        int s = csr_src[j];
        float rs = rs_out[s];
        ushort4 u = ((const ushort4*)(hn + (size_t)s*HD))[lane];
        ax = fmaf(bits2f(u.x), rs, ax);
        ay = fmaf(bits2f(u.y), rs, ay);
        az = fmaf(bits2f(u.z), rs, az);
        aw = fmaf(bits2f(u.w), rs, aw);
    }
    int db = dcode[5], fg = dcode[2];
    float rsn = rs_in[n];
    int c = lane*4;
    ax = fmaxf(fmaf(ax, rsn, ldf3(b_conv, c+0, db)), 0.f);
    ay = fmaxf(fmaf(ay, rsn, ldf3(b_conv, c+1, db)), 0.f);
    az = fmaxf(fmaf(az, rsn, ldf3(b_conv, c+2, db)), 0.f);
    aw = fmaxf(fmaf(aw, rsn, ldf3(b_conv, c+3, db)), 0.f);
    float4 v; v.x = ax; v.y = ay; v.z = az; v.w = aw;
    ((float4*)(hr + (size_t)n*HD))[lane] = v;
    float g = ax*ldf3(w_gate, c+0, fg) + ay*ldf3(w_gate, c+1, fg)
            + az*ldf3(w_gate, c+2, fg) + aw*ldf3(w_gate, c+3, fg);
    #pragma unroll
    for (int off = 32; off; off >>= 1) g += __shfl_down(g, off);
    if (lane == 0) gate[n] = g + ldf3(b_gate, 0, db);
}

__global__ __launch_bounds__(256) void k_hg(const float* __restrict__ att,
                                            const float* __restrict__ hr,
                                            const int* __restrict__ gstart,
                                            const int* __restrict__ gend,
                                            float* __restrict__ hg){
    int g = blockIdx.x >> 3, part = blockIdx.x & 7;
    int c = threadIdx.x;
    int s = gstart[g], en = gend[g];
    int len = en - s;
    if (len <= 0) return;
    int chunk = (len + 7) >> 3;
    int lo = s + part*chunk, hi = min(lo + chunk, en);
    if (lo >= hi) return;
    float acc = 0.f;
    for (int n = lo; n < hi; n++) acc += att[n] * hr[(size_t)n*HD + c];
    atomicAdd(&hg[g*HD + c], acc);
}

__global__ __launch_bounds__(256) void k_cls(const float* __restrict__ hg,
                                             const void* __restrict__ W1,
                                             const void* __restrict__ b1,
                                             const void* __restrict__ W2,
                                             const void* __restrict__ b2,
                                             const int* __restrict__ dcode,
                                             float* __restrict__ out0,
                                             float* __restrict__ out_hg){
    int f1 = dcode[3], f2 = dcode[4], db = dcode[5];
    int g = blockIdx.x, tid = threadIdx.x;
    __shared__ float hs[256];
    float hv = hg[g*HD + tid];
    hs[tid] = hv;
    out_hg[g*HD + tid] = hv;
    __syncthreads();
    float acc = ldf3(b1, tid, db);
    if (f1 == 1){
        const bf16* w = (const bf16*)W1;
        for (int k = 0; k < HD; k++) acc += hs[k]*b2f(w[(size_t)k*HD + tid]);
    } else if (f1 == 2){
        const __half* w = (const __half*)W1;
        for (int k = 0; k < HD; k++) acc += hs[k]*__half2float(w[(size_t)k*HD + tid]);
    } else {
        const float* w = (const float*)W1;
        for (int k = 0; k < HD; k++) acc += hs[k]*w[(size_t)k*HD + tid];
    }
    float p0 = acc * ldf3(W2, tid*CC + 0, f2);
    float p1 = acc * ldf3(W2, tid*CC + 1, f2);
    __shared__ float r0[256], r1[256];
    r0[tid] = p0; r1[tid] = p1; __syncthreads();
    for (int s = 128; s; s >>= 1){
        if (tid < s){ r0[tid] += r0[tid+s]; r1[tid] += r1[tid+s]; }
        __syncthreads();
    }
    if (tid == 0){
        out0[g*CC+0] = 1.f/(1.f + expf(-(r0[0] + ldf3(b2, 0, db))));
        out0[g*CC+1] = 1.f/(1.f + expf(-(r1[0] + ldf3(b2, 1, db))));
    }
}

extern "C" void kernel_launch(void* const* d_in, const int* in_sizes, int n_in,
                              void* d_out, int out_size, void* d_ws, size_t ws_size,
                              hipStream_t stream) {
    const void* h      = d_in[0];
    const void* src_r  = d_in[1];
    const void* dst_r  = d_in[2];
    const void* gid_r  = d_in[3];
    const void* W_conv = d_in[4];
    const void* b_conv = d_in[5];
    const void* w_gate = d_in[6];
    const void* b_gate = d_in[7];
    const void* W1     = d_in[8];
    const void* b1     = d_in[9];
    const void* W2     = d_in[10];
    const void* b2     = d_in[11];

    float* out     = (float*)d_out;      // fp32 output (established R10)
    float* out0    = out;                // [G,C]
    float* out_att = out + GG*CC;        // [N]
    float* out_hg  = out + GG*CC + NN;   // [G,H]

    char* w = (char*)d_ws;
    float* hr   = (float*)w;  w += (size_t)NN*HD*sizeof(float);
    bf16*  hn   = (bf16*)w;   w += (size_t)NN*HD*sizeof(bf16);
    bf16*  Wb   = (bf16*)w;   w += (size_t)IND*HD*sizeof(bf16);
    float* rs_o = (float*)w;  w += (size_t)NN*sizeof(float);
    float* rs_i = (float*)w;  w += (size_t)NN*sizeof(float);
    float* gate = (float*)w;  w += (size_t)NN*sizeof(float);
    float* hg   = (float*)w;  w += (size_t)GG*HD*sizeof(float);
    int* gstart = (int*)w;    w += GG*sizeof(int);
    int* gend   = (int*)w;    w += GG*sizeof(int);
    int* dcode  = (int*)w;    w += 8*sizeof(int);
    int* icode  = (int*)w;    w += 8*sizeof(int);
    int* src_i  = (int*)w;    w += (size_t)EE*sizeof(int);
    int* dst_i  = (int*)w;    w += (size_t)EE*sizeof(int);
    int* gid_i  = (int*)w;    w += (size_t)NN*sizeof(int);
    int* cnt_out= (int*)w;    w += (size_t)NN*sizeof(int);
    int* cnt_in = (int*)w;    w += (size_t)NN*sizeof(int);
    int* cursor = (int*)w;    w += (size_t)NN*sizeof(int);
    int* rowst  = (int*)w;    w += (size_t)(NN+1)*sizeof(int);
    int* csr    = (int*)w;    w += (size_t)EE*sizeof(int);

    k_dtype<<<1, 64, 0, stream>>>((const unsigned short*)h, (const unsigned short*)W_conv,
                                  (const unsigned short*)w_gate, (const unsigned short*)W1,
                                  (const unsigned short*)W2, (const unsigned short*)b_conv,
                                  dcode);
    k_idet<<<3, 64, 0, stream>>>(src_r, dst_r, gid_r, icode);

    hipMemsetAsync(hg, 0, (size_t)GG*HD*sizeof(float), stream);
    hipMemsetAsync(cnt_out, 0, (size_t)3*NN*sizeof(int), stream);  // cnt_out+cnt_in+cursor

    k_prep<<<(EE+255)/256, 256, 0, stream>>>(src_r, dst_r, gid_r, icode,
                                             src_i, dst_i, gid_i, cnt_out, cnt_in);
    k_rs<<<(NN+255)/256, 256, 0, stream>>>(cnt_out, cnt_in, rs_o, rs_i);
    k_scan<<<1, 256, 0, stream>>>(cnt_in, rowst);
    k_fill<<<(EE+255)/256, 256, 0, stream>>>(src_i, dst_i, rowst, cursor, csr);
    k_lb<<<1, 128, 0, stream>>>(gid_i, gstart, gend);

    k_wprep<<<IND, HD, 0, stream>>>(W_conv, dcode, Wb);
    k_gemm1m<<<(NN+63)/64, 256, 0, stream>>>(h, Wb, dcode, hn);

    k_gather<<<(NN+3)/4, 256, 0, stream>>>(hn, rs_o, rs_i, rowst, csr,
                                           b_conv, w_gate, b_gate, dcode, hr, gate);

    k_soft<<<GG, 256, 0, stream>>>(gstart, gend, gate, out_att);
    k_hg<<<GG*8, 256, 0, stream>>>(gate, hr, gstart, gend, hg);
    k_cls<<<GG, 256, 0, stream>>>(hg, W1, b1, W2, b2, dcode, out0, out_hg);
}